// Round 4
// baseline (7389.687 us; speedup 1.0000x reference)
//
#include <hip/hip_runtime.h>
#include <stdint.h>

#define EMBED  256
#define HIDDEN 512
#define BATCH  64
#define SEQ    512

typedef _Float16 f16x8 __attribute__((ext_vector_type(8)));
typedef _Float16 f16x4 __attribute__((ext_vector_type(4)));
typedef float    f32x4 __attribute__((ext_vector_type(4)));

// ---------------------------------------------------------------------------
// wih (gemm, K32 conv): frag[(s*32+nt)*64+lane] f16x8, elem j =
//   W_ih[k=s*32+(l>>4)*8+j][col=nt*16+(l&15)]
// whh16 (rnn, K16 conv): frag[(kp*32+mt)*64+lane] f16x4, elem q =
//   W_hh[k=kp*16+(l>>4)*4+q][j=mt*16+(l&15)]
// 16x16 C/D: col=lane&15, row=(lane>>4)*4+reg  == K16 B-frag layout (identity
// republish: producer's D fragment IS the consumer's B fragment).
// ---------------------------------------------------------------------------

#define WIH_FRAGS   (8 * 32 * 64 * 8)     // 131072 f16 = 256 KB
#define WHH16_ELEMS (32 * 32 * 64 * 4)    // 262144 f16 = 512 KB

__global__ void prep_pack(const float* __restrict__ W_ih,
                          const float* __restrict__ W_hh,
                          unsigned short* __restrict__ wih_p,
                          unsigned short* __restrict__ whh16) {
    int tid = blockIdx.x * blockDim.x + threadIdx.x;
    if (tid < WIH_FRAGS) {
        int j = tid & 7, l = (tid >> 3) & 63, nt = (tid >> 9) & 31, s = tid >> 14;
        int k   = s * 32 + ((l >> 4) << 3) + j;
        int col = (nt << 4) + (l & 15);
        wih_p[tid] = __builtin_bit_cast(unsigned short, (_Float16)W_ih[k * HIDDEN + col]);
    } else {
        int t2 = tid - WIH_FRAGS;
        if (t2 < WHH16_ELEMS) {
            int q = t2 & 3, l = (t2 >> 2) & 63, mt = (t2 >> 8) & 31, kp = t2 >> 13;
            int k   = kp * 16 + ((l >> 4) << 2) + q;
            int col = (mt << 4) + (l & 15);
            whh16[t2] = __builtin_bit_cast(unsigned short, (_Float16)W_hh[k * HIDDEN + col]);
        }
    }
}

// ---------------------------------------------------------------------------
// Kernel A: pre = embed @ W_ih + (b_ih + b_hh), plain f32 into d_out rows.
// (R1 epilogue — validated.)
// ---------------------------------------------------------------------------
__global__ __launch_bounds__(256) void enc_gemm_ih(
    const int* __restrict__ source,
    const float* __restrict__ embedding,
    const unsigned short* __restrict__ wih_p,
    const float* __restrict__ b_ih,
    const float* __restrict__ b_hh,
    float* __restrict__ out)
{
    const int lane = threadIdx.x & 63;
    const int mt   = (blockIdx.x << 2) + (threadIdx.x >> 6);
    const int r0   = mt << 4;
    const int g    = lane >> 4;
    const int c    = lane & 15;

    const int idx = source[r0 + c];
    const float* erow = embedding + (size_t)idx * EMBED;

    f16x8 afrag[8];
#pragma unroll
    for (int s = 0; s < 8; ++s) {
        const float* p = erow + (s << 5) + (g << 3);
        f32x4 f0 = *(const f32x4*)p;
        f32x4 f1 = *(const f32x4*)(p + 4);
        f16x8 a;
        a[0] = (_Float16)f0[0]; a[1] = (_Float16)f0[1];
        a[2] = (_Float16)f0[2]; a[3] = (_Float16)f0[3];
        a[4] = (_Float16)f1[0]; a[5] = (_Float16)f1[1];
        a[6] = (_Float16)f1[2]; a[7] = (_Float16)f1[3];
        afrag[s] = a;
    }

    const f16x8* wp = (const f16x8*)wih_p;
    for (int nt = 0; nt < 32; ++nt) {
        f32x4 acc = {0.f, 0.f, 0.f, 0.f};
#pragma unroll
        for (int s = 0; s < 8; ++s) {
            f16x8 bfr = wp[(((s << 5) + nt) << 6) + lane];
            acc = __builtin_amdgcn_mfma_f32_16x16x32_f16(afrag[s], bfr, acc, 0, 0, 0);
        }
        const int col  = (nt << 4) + c;
        const float bias = b_ih[col] + b_hh[col];
        float* o = out + (size_t)(r0 + (g << 2)) * HIDDEN + col;
#pragma unroll
        for (int r = 0; r < 4; ++r)
            o[(size_t)r * HIDDEN] = acc[r] + bias;
    }
}

__global__ void zero_flags(unsigned int* __restrict__ flags) {
    flags[threadIdx.x] = 0;   // 128 = 4 groups x 32 planes
}

// ---------------------------------------------------------------------------
// Kernel B: recurrence. 4 groups x 8 j-slices = 32 active blocks (grid 64,
// blockIdx&7>=4 exit so each group's slices share an XCD). Block = 4 waves;
// wave owns m-tile mt = p*4+w (16 j = one k16-plane). Weights fully
// register-resident. Publish h plane = one f16x4 store/lane (C/D==B layout).
// Per-plane flag sync; no LDS, no barriers.
// ---------------------------------------------------------------------------
__global__ __launch_bounds__(256, 1) void enc_rnn(
    const unsigned short* __restrict__ whh16,
    unsigned short* __restrict__ hgbuf,       // [4][2][32][64] f16x4 = 128 KB
    unsigned int* __restrict__ flags,         // [4][32]
    float* __restrict__ out)
{
    const int gq = blockIdx.x & 7;
    if (gq >= 4) return;
    const int grp  = gq;
    const int p    = blockIdx.x >> 3;          // slice 0..7
    const int lane = threadIdx.x & 63;
    const int w    = threadIdx.x >> 6;         // 0..3
    const int mt   = (p << 2) + w;             // plane / m-tile 0..31
    const int c    = lane & 15;

    // A-fragments: all 32 k16-planes of this wave's 16 j's (64 regs)
    f16x4 wa[32];
    const f16x4* wp = (const f16x4*)whh16;
#pragma unroll
    for (int kp = 0; kp < 32; ++kp)
        wa[kp] = wp[(kp * 32 + mt) * 64 + lane];

    f16x4* hgG = (f16x4*)hgbuf + (size_t)grp * 2 * 32 * 64;
    unsigned int* fl = flags + grp * 32;

    // chain b = grp*16 + c; this lane's 4 rows j = mt*16 + (lane>>4)*4 + r
    float* gaddr = out + (size_t)(grp * 16 + c) * SEQ * HIDDEN
                 + (mt << 4) + ((lane >> 4) << 2);

#pragma unroll 1
    for (int t = 1; t <= SEQ; ++t) {
        f32x4 pre = *(const f32x4*)gaddr;      // independent of flags: issues early
        f32x4 acc0 = {0.f, 0.f, 0.f, 0.f}, acc1 = {0.f, 0.f, 0.f, 0.f};

        if (t > 1) {
            const unsigned want = (unsigned)(t - 1);
            while (true) {
                unsigned v = 0xFFFFFFFFu;
                if (lane < 32)
                    v = __hip_atomic_load(&fl[lane], __ATOMIC_RELAXED,
                                          __HIP_MEMORY_SCOPE_AGENT);
                if (!__ballot(v < want)) break;
            }
            __threadfence();                   // acquire: order + L1 inval

            const f16x4* hb = hgG + (size_t)((t - 1) & 1) * 32 * 64 + lane;
#pragma unroll
            for (int kp = 0; kp < 32; kp += 2) {
                f16x4 b0 = hb[(size_t)kp * 64];
                f16x4 b1 = hb[(size_t)(kp + 1) * 64];
                acc0 = __builtin_amdgcn_mfma_f32_16x16x16f16(wa[kp],     b0, acc0, 0, 0, 0);
                acc1 = __builtin_amdgcn_mfma_f32_16x16x16f16(wa[kp + 1], b1, acc1, 0, 0, 0);
            }
        }

        f32x4 x = acc0 + acc1 + pre;
        f32x4 hf;
        f16x4 h16;
#pragma unroll
        for (int r = 0; r < 4; ++r) {
            float e  = __expf(2.0f * x[r]);
            float th = 1.0f - 2.0f * __builtin_amdgcn_rcpf(e + 1.0f);   // tanh
            hf[r] = th;
            h16[r] = (_Float16)th;
        }
        *(f32x4*)gaddr = hf;                                  // f32 h over pre
        hgG[(size_t)(t & 1) * 32 * 64 + mt * 64 + lane] = h16;  // publish plane
        __threadfence();                                      // release
        if (lane == 0)
            __hip_atomic_store(&fl[mt], (unsigned)t, __ATOMIC_RELAXED,
                               __HIP_MEMORY_SCOPE_AGENT);
        gaddr += HIDDEN;
    }
}

extern "C" void kernel_launch(void* const* d_in, const int* in_sizes, int n_in,
                              void* d_out, int out_size, void* d_ws, size_t ws_size,
                              hipStream_t stream) {
    const int*   source    = (const int*)d_in[0];
    const float* embedding = (const float*)d_in[1];
    const float* W_ih      = (const float*)d_in[2];
    const float* W_hh      = (const float*)d_in[3];
    const float* b_ih      = (const float*)d_in[4];
    const float* b_hh      = (const float*)d_in[5];
    float* out = (float*)d_out;

    char* ws = (char*)d_ws;
    // [0,256K): wih_p during prep+gemm; reused as hg[0,128K)+flags[128K,+512B)
    // by enc_rnn (zero_flags launched after gemm). [256K,768K): whh16.
    unsigned short* wih_p = (unsigned short*)ws;
    unsigned short* hg    = (unsigned short*)ws;
    unsigned int*   flags = (unsigned int*)(ws + 131072);
    unsigned short* whh16 = (unsigned short*)(ws + 262144);

    prep_pack<<<(WIH_FRAGS + WHH16_ELEMS) / 256, 256, 0, stream>>>(W_ih, W_hh, wih_p, whh16);
    enc_gemm_ih<<<512, 256, 0, stream>>>(source, embedding, wih_p, b_ih, b_hh, out);
    zero_flags<<<1, 128, 0, stream>>>(flags);
    enc_rnn<<<64, 256, 0, stream>>>(whh16, hg, flags, out);
}

// Round 5
// 1298.926 us; speedup vs baseline: 5.6891x; 5.6891x over previous
//
#include <hip/hip_runtime.h>
#include <stdint.h>

#define EMBED  256
#define HIDDEN 512
#define BATCH  64
#define SEQ    512

typedef _Float16 f16x8 __attribute__((ext_vector_type(8)));
typedef _Float16 f16x4 __attribute__((ext_vector_type(4)));
typedef float    f32x4 __attribute__((ext_vector_type(4)));

// ---------------------------------------------------------------------------
// Fragment packing (A and B share it; permutation-safe):
//   frag[(s*32 + mt)*64 + lane] is an f16x8; element j holds
//     W[k = s*32 + (lane>>4)*8 + j][col = mt*16 + (lane&15)]
// C/D: col = lane&15, row = (lane>>4)*4 + reg.
// ---------------------------------------------------------------------------

#define WIH_FRAGS (8 * 32 * 64 * 8)
#define WHH_FRAGS (16 * 32 * 64 * 8)

__global__ void prep_pack(const float* __restrict__ W_ih,
                          const float* __restrict__ W_hh,
                          unsigned short* __restrict__ wih_p,
                          unsigned short* __restrict__ whh_p) {
    int tid = blockIdx.x * blockDim.x + threadIdx.x;
    if (tid < WIH_FRAGS) {
        int j = tid & 7, l = (tid >> 3) & 63, nt = (tid >> 9) & 31, s = tid >> 14;
        int k   = s * 32 + ((l >> 4) << 3) + j;
        int col = (nt << 4) + (l & 15);
        wih_p[tid] = __builtin_bit_cast(unsigned short, (_Float16)W_ih[k * HIDDEN + col]);
    } else {
        int t2 = tid - WIH_FRAGS;
        if (t2 < WHH_FRAGS) {
            int j = t2 & 7, l = (t2 >> 3) & 63, mt = (t2 >> 9) & 31, s = t2 >> 14;
            int k   = s * 32 + ((l >> 4) << 3) + j;
            int col = (mt << 4) + (l & 15);
            whh_p[t2] = __builtin_bit_cast(unsigned short, (_Float16)W_hh[k * HIDDEN + col]);
        }
    }
}

// ---------------------------------------------------------------------------
// Kernel A: pre = embed @ W_ih + (b_ih + b_hh), f16 in HIGH 1KB of each 2KB
// out row (validated R2/R3).
// ---------------------------------------------------------------------------
__global__ __launch_bounds__(256) void enc_gemm_ih(
    const int* __restrict__ source,
    const float* __restrict__ embedding,
    const unsigned short* __restrict__ wih_p,
    const float* __restrict__ b_ih,
    const float* __restrict__ b_hh,
    float* __restrict__ out)
{
    const int lane = threadIdx.x & 63;
    const int mt   = (blockIdx.x << 2) + (threadIdx.x >> 6);
    const int r0   = mt << 4;
    const int g    = lane >> 4;
    const int c    = lane & 15;

    const int idx = source[r0 + c];
    const float* erow = embedding + (size_t)idx * EMBED;

    f16x8 afrag[8];
#pragma unroll
    for (int s = 0; s < 8; ++s) {
        const float* p = erow + (s << 5) + (g << 3);
        f32x4 f0 = *(const f32x4*)p;
        f32x4 f1 = *(const f32x4*)(p + 4);
        f16x8 a;
        a[0] = (_Float16)f0[0]; a[1] = (_Float16)f0[1];
        a[2] = (_Float16)f0[2]; a[3] = (_Float16)f0[3];
        a[4] = (_Float16)f1[0]; a[5] = (_Float16)f1[1];
        a[6] = (_Float16)f1[2]; a[7] = (_Float16)f1[3];
        afrag[s] = a;
    }

    const f16x8* wp = (const f16x8*)wih_p;
    for (int nt = 0; nt < 32; ++nt) {
        f32x4 acc = {0.f, 0.f, 0.f, 0.f};
#pragma unroll
        for (int s = 0; s < 8; ++s) {
            f16x8 bfr = wp[(((s << 5) + nt) << 6) + lane];
            acc = __builtin_amdgcn_mfma_f32_16x16x32_f16(afrag[s], bfr, acc, 0, 0, 0);
        }
        const int col  = (nt << 4) + c;
        const float bias = b_ih[col] + b_hh[col];
        char* ob = (char*)out + (size_t)(r0 + (g << 2)) * 2048 + 1024 + (col << 1);
#pragma unroll
        for (int r = 0; r < 4; ++r)
            *(_Float16*)(ob + (size_t)r * 2048) = (_Float16)(acc[r] + bias);
    }
}

// ---------------------------------------------------------------------------
// Kernel B: recurrence. 4 blocks x 16 chains, 8 waves; wave w owns m-tiles
// mt = w*4+m. Weight tiers per wave: s0..8 VGPR-pinned (36 frags, 144 regs,
// asm keep-alive so the compiler cannot sink the loads into the loop);
// s9..11 LDS (96 KB); s12..15 streamed from L2 (staggered issue).
// h double-buffered in LDS [2][16][1024B], XOR-swizzled 16B chunks (u ^ cx)
// (validated R2). One barrier per step.
// ---------------------------------------------------------------------------
__global__ __launch_bounds__(512, 1) void enc_rnn(
    const unsigned short* __restrict__ whh_p,
    float* __restrict__ out)
{
    extern __shared__ char lds[];
    char* hbase = lds;            // 32 KB: [2][16][1024B], swizzled
    char* wbase = lds + 32768;    // 96 KB: (w*12 + fid)*1024 + lane*16

    const int tid  = threadIdx.x;
    const int lane = tid & 63;
    const int w    = tid >> 6;
    const int g    = lane >> 4;
    const int c    = lane & 15;      // chain
    const int cx   = c & 7;
    const int mt0  = w << 2;

    const f16x8* wp = (const f16x8*)whh_p;

    // LDS tier: s = 9..11
    {
        char* wl0 = wbase + ((w * 12) << 10) + (lane << 4);
#pragma unroll
        for (int fid = 0; fid < 12; ++fid) {
            int s = 9 + (fid >> 2), m = fid & 3;
            *(f16x8*)(wl0 + (fid << 10)) = wp[((s * 32 + mt0 + m) << 6) + lane];
        }
    }
    // zero both h buffers (h_0 = 0)
    for (int i = tid; i < 32768 / 4; i += 512) ((int*)hbase)[i] = 0;

    // VGPR tier: s = 0..8, pinned live via opaque asm defs (no sink/remat)
    f16x8 wreg[36];
#pragma unroll
    for (int s = 0; s < 9; ++s)
#pragma unroll
        for (int m = 0; m < 4; ++m)
            wreg[s * 4 + m] = wp[((s * 32 + mt0 + m) << 6) + lane];
#pragma unroll
    for (int i = 0; i < 36; ++i)
        asm volatile("" : "+v"(wreg[i]));

    __syncthreads();

    // ---- t-invariant addresses ----
    // h-read: chunk u = 4s+g, phys = u^cx -> addr = c*1024 + (s^(cx>>2))*64
    //         + ((g^(cx&3))*16; even s from hev(+ch*64), odd s from hod(-ch*64)
    const int ch = cx >> 2;
    char* hb2 = hbase + (c << 10) + ((g ^ (cx & 3)) << 4);
    char* hev = hb2 + (ch << 6);
    char* hod = hb2 - (ch << 6);
    // h-write: chunk u = w*8 + m*2 + (g>>1), phys = u^cx
    char* hw[4];
#pragma unroll
    for (int m = 0; m < 4; ++m) {
        int u = (w << 3) | ((m ^ (cx >> 1)) << 1) | ((g >> 1) ^ (cx & 1));
        hw[m] = hbase + (c << 10) + (u << 4) + ((g & 1) << 3);
    }
    // global row (2KB): chain b = blk*16+c; slot byte 2*j, j = w*64+m*16+g*4
    char* ga = (char*)out + (size_t)((blockIdx.x << 4) + c) * SEQ * 2048
             + (w << 7) + (g << 3);
    // stream bases s = 12..15
    const char* sp12 = (const char*)whh_p + ((12 * 32 + mt0) << 10) + (lane << 4);
    const char* sp13 = (const char*)whh_p + ((13 * 32 + mt0) << 10) + (lane << 4);
    const char* sp14 = (const char*)whh_p + ((14 * 32 + mt0) << 10) + (lane << 4);
    const char* sp15 = (const char*)whh_p + ((15 * 32 + mt0) << 10) + (lane << 4);
    char* wl = wbase + ((w * 12) << 10) + (lane << 4);

    auto STEP = [&](int RB, int RBN, int TB) {
        f16x8 sA[4], sB[4], sC[4];
#pragma unroll
        for (int m = 0; m < 4; ++m) sA[m] = *(const f16x8*)(sp12 + (m << 10));
#pragma unroll
        for (int m = 0; m < 4; ++m) sB[m] = *(const f16x8*)(sp13 + (m << 10));
        f16x4 pre[4];
#pragma unroll
        for (int m = 0; m < 4; ++m)
            pre[m] = *(const f16x4*)(ga + TB + 1024 + (m << 5));

        f32x4 acc[4];
#pragma unroll
        for (int m = 0; m < 4; ++m) acc[m] = (f32x4){0.f, 0.f, 0.f, 0.f};

#pragma unroll
        for (int s = 0; s < 16; ++s) {
            f16x8 h = *(const f16x8*)(((s & 1) ? hod : hev) + (s << 6) + RB);
            if (s == 6) {    // stream s14 (consumed at s==14)
#pragma unroll
                for (int m = 0; m < 4; ++m) sC[m] = *(const f16x8*)(sp14 + (m << 10));
            }
#pragma unroll
            for (int m = 0; m < 4; ++m) {
                f16x8 wv;
                if (s < 9)        wv = wreg[s * 4 + m];
                else if (s < 12)  wv = *(const f16x8*)(wl + ((((s - 9) << 2) | m) << 10));
                else if (s == 12) wv = sA[m];
                else if (s == 13) wv = sB[m];
                else if (s == 14) wv = sC[m];
                else              wv = sA[m];   // s15: refilled below
                acc[m] = __builtin_amdgcn_mfma_f32_16x16x32_f16(wv, h, acc[m], 0, 0, 0);
            }
            if (s == 12) {   // refill sA <- s15 (gap 3 s-groups > L2 latency)
#pragma unroll
                for (int m = 0; m < 4; ++m) sA[m] = *(const f16x8*)(sp15 + (m << 10));
            }
        }

        // epilogue: h = tanh(acc + pre); f16 to out low half + LDS next buf
#pragma unroll
        for (int m = 0; m < 4; ++m) {
            f16x4 hv;
#pragma unroll
            for (int r = 0; r < 4; ++r) {
                float x  = acc[m][r] + (float)pre[m][r];
                float e  = __expf(2.0f * x);
                hv[r] = (_Float16)(1.0f - 2.0f * __builtin_amdgcn_rcpf(e + 1.0f));
            }
            *(f16x4*)(ga + TB + (m << 5)) = hv;
            *(f16x4*)(hw[m] + RBN) = hv;
        }
        __syncthreads();
    };

#pragma unroll 1
    for (int tp = 0; tp < SEQ; tp += 2) {
        STEP(0, 16384, 0);
        STEP(16384, 0, 2048);
        ga += 4096;
    }
}

// ---------------------------------------------------------------------------
// Kernel C: in-place expand f16 h (row bytes [0,1024)) -> f32 row.
// ---------------------------------------------------------------------------
__global__ __launch_bounds__(256) void expand_rows(float* __restrict__ out) {
    const int lane = threadIdx.x & 63;
    const int row  = (blockIdx.x << 2) + (threadIdx.x >> 6);
    char* rp = (char*)out + ((size_t)row << 11);
    f16x8 v = *(const f16x8*)(rp + (lane << 4));
    f32x4 lo, hi;
#pragma unroll
    for (int i = 0; i < 4; ++i) { lo[i] = (float)v[i]; hi[i] = (float)v[i + 4]; }
    *(f32x4*)(rp + (lane << 5))      = lo;
    *(f32x4*)(rp + (lane << 5) + 16) = hi;
}

extern "C" void kernel_launch(void* const* d_in, const int* in_sizes, int n_in,
                              void* d_out, int out_size, void* d_ws, size_t ws_size,
                              hipStream_t stream) {
    const int*   source    = (const int*)d_in[0];
    const float* embedding = (const float*)d_in[1];
    const float* W_ih      = (const float*)d_in[2];
    const float* W_hh      = (const float*)d_in[3];
    const float* b_ih      = (const float*)d_in[4];
    const float* b_hh      = (const float*)d_in[5];
    float* out = (float*)d_out;

    unsigned short* wih_p = (unsigned short*)d_ws;          // 256 KB
    unsigned short* whh_p = wih_p + WIH_FRAGS;              // 512 KB

    prep_pack<<<(WIH_FRAGS + WHH_FRAGS) / 256, 256, 0, stream>>>(W_ih, W_hh, wih_p, whh_p);
    enc_gemm_ih<<<512, 256, 0, stream>>>(source, embedding, wih_p, b_ih, b_hh, out);
    enc_rnn<<<4, 512, 131072, stream>>>(whh_p, out);
    expand_rows<<<8192, 256, 0, stream>>>(out);
}